// Round 10
// baseline (21.709 us; speedup 1.0000x reference)
//
#include <hip/hip_runtime.h>

namespace {
constexpr int GS = 128;
constexpr int NPTS = GS * GS;          // 16384 points per grid
constexpr float RES = 0.25f;
constexpr int NGRIDS = 16;
constexpr int BLOCK = 1024;
constexpr int ROWS_PER_BLOCK = BLOCK / GS;     // 8 query rows per block
constexpr int CHUNKS = NPTS / BLOCK;           // 16 chunks per (grid,dir)
constexpr int NBLOCKS = NGRIDS * 2 * CHUNKS;   // 512
constexpr int SLAB_ROWS = 14;                  // max rows a block's windows touch
}

// Single compute kernel; per-block sums go straight to *out via the NATIVE
// fp32 atomic (unsafeAtomicAdd -> global_atomic_add_f32, fire-and-forget —
// NOT the CAS-loop IEEE atomicAdd that serialized in R7). out is zeroed by a
// 4-byte memset node each replay.
// One thread per query point; 512 x 1024-thread blocks (2 blocks/CU = 32
// waves/CU). Block's <=14-row DB slab (7 KB) staged to LDS in one coalesced
// burst; phase A's 49 reads are imm-offset ds_read_b32.
// Phase A: 7x7 SUPERSET window at clamped base (rb,cb) — always in-grid,
// covers the clamped radius-3 neighborhood. Exact-done iff best <= (4*RES)^2
// = 1.0 (excluded cells: Chebyshev >= 4 -> planar >= 1.0). Phase B:
// wave-cooperative straggler scan from GLOBAL memory (rare); one pass with
// K = ceil(4*sqrt(bestA)) is exact (radius >= K -> planar >= bestA).
__global__ __launch_bounds__(BLOCK, 8) void chamfer_kernel(
    const float* __restrict__ pred, const float* __restrict__ gt,
    float* __restrict__ out)
{
    __shared__ float slab[SLAB_ROWS * GS];     // 7168 B

    const int bid = blockIdx.x;
    const int chunk = bid & (CHUNKS - 1);
    const int pair = bid >> 4;             // CHUNKS = 16
    const int g = pair >> 1;
    const int dir = pair & 1;
    const float* __restrict__ A  = (dir == 0) ? gt + g * NPTS : pred + g * NPTS;
    const float* __restrict__ DB = (dir == 0) ? pred + g * NPTS : gt + g * NPTS;

    const int tid = threadIdx.x;
    const int r0 = chunk * ROWS_PER_BLOCK;
    const int rlo = max(r0 - 3, 0);
    const int rhi = min(r0 + ROWS_PER_BLOCK + 2, GS - 1);  // r0+7 rows, +3 window
    const int nrow = rhi - rlo + 1;                        // <= 14

    // stage slab rows [rlo..rhi] as float4s: <=448 loads, fully coalesced
    if (tid < nrow * (GS / 4)) {
        const int row = tid >> 5;          // GS/4 = 32 quads per row
        const int c4  = tid & 31;
        reinterpret_cast<float4*>(slab)[tid] =
            reinterpret_cast<const float4*>(DB + (rlo + row) * GS)[c4];
    }
    __syncthreads();

    const int i = chunk * BLOCK + tid;
    const int ri = r0 + (tid >> 7);
    const int ci = tid & (GS - 1);
    const float za = A[i];

    // superset window base: clamp the BASE, not each cell
    const int rb = min(max(ri, 3), GS - 4);
    const int cb = min(max(ci, 3), GS - 4);
    const float* __restrict__ wbase = slab + (rb - 3 - rlo) * GS + (cb - 3);

    // per-axis planar terms
    float dx2[7], dy2[7];
    #pragma unroll
    for (int t = 0; t < 7; ++t) {
        const float dx = (float)(ri - (rb - 3 + t)) * RES;
        dx2[t] = dx * dx;
        const float dy = (float)(ci - (cb - 3 + t)) * RES;
        dy2[t] = dy * dy;
    }

    // phase A: 49 ds_read_b32 with imm offsets off one base; per-row min fold
    float bacc[4] = {1e30f, 1e30f, 1e30f, 1e30f};
    #pragma unroll
    for (int a = 0; a < 7; ++a) {
        float rm0 = 1e30f, rm1 = 1e30f;
        #pragma unroll
        for (int b = 0; b < 7; ++b) {
            const float z = wbase[a * GS + b];      // ds imm offset a*512+b*4
            const float dz = za - z;
            const float v = fmaf(dz, dz, dy2[b]);
            if (b & 1) rm1 = fminf(rm1, v); else rm0 = fminf(rm0, v);
        }
        bacc[a & 3] = fminf(bacc[a & 3], fminf(rm0, rm1) + dx2[a]);
    }
    float best = fminf(fminf(bacc[0], bacc[1]), fminf(bacc[2], bacc[3]));

    // phase B: wave-cooperative straggler finish (rare), from global
    const int lane = tid & 63;
    const int lr = lane >> 3, lc = lane & 7;   // 8x8 lane tile
    unsigned long long pend = __ballot(best > 1.0f);
    while (pend) {
        const int src = __ffsll(pend) - 1;
        pend &= pend - 1;
        const int qri = __shfl(ri, src);
        const int qci = __shfl(ci, src);
        const float qza = __shfl(za, src);
        const float qb  = __shfl(best, src);
        int K = (int)(4.0f * sqrtf(qb)) + 1;   // >= ceil(4*sqrt(qb))
        K = min(K, GS - 1);
        float m = 1e30f;
        for (int tr = -K; tr <= K; tr += 8) {
            const int dr = tr + lr;
            if (dr > K) continue;
            const int r = min(max(qri + dr, 0), GS - 1);
            const float dx = (float)(qri - r) * RES;
            const float dxx2 = dx * dx;
            const float* __restrict__ row = DB + r * GS;
            for (int tc = -K; tc <= K; tc += 8) {
                const int dc = tc + lc;
                if (dc > K) continue;
                const int c = min(max(qci + dc, 0), GS - 1);
                const float dy = (float)(qci - c) * RES;
                const float dz = qza - row[c];
                m = fminf(m, fmaf(dz, dz, fmaf(dy, dy, dxx2)));
            }
        }
        #pragma unroll
        for (int off = 32; off > 0; off >>= 1) m = fminf(m, __shfl_xor(m, off));
        if (lane == src) best = fminf(best, m);
    }

    // block sum-reduction -> ONE native fp32 atomic per block
    for (int off = 32; off > 0; off >>= 1) best += __shfl_down(best, off);
    __shared__ float wsum[BLOCK / 64];
    if ((tid & 63) == 0) wsum[tid >> 6] = best;
    __syncthreads();
    if (tid == 0) {
        float s = 0.0f;
        #pragma unroll
        for (int w = 0; w < BLOCK / 64; ++w) s += wsum[w];
        unsafeAtomicAdd(out, s * (1.0f / NGRIDS));  // global_atomic_add_f32
    }
}

extern "C" void kernel_launch(void* const* d_in, const int* in_sizes, int n_in,
                              void* d_out, int out_size, void* d_ws, size_t ws_size,
                              hipStream_t stream) {
    const float* pred = (const float*)d_in[0];  // inputs (1,1,512,512)
    const float* gt   = (const float*)d_in[1];  // targets (1,512,512)
    float* out = (float*)d_out;
    hipMemsetAsync(out, 0, sizeof(float), stream);   // graph memset node
    chamfer_kernel<<<NBLOCKS, BLOCK, 0, stream>>>(pred, gt, out);
}

// Round 11
// 20.248 us; speedup vs baseline: 1.0721x; 1.0721x over previous
//
#include <hip/hip_runtime.h>

namespace {
constexpr int GS = 128;
constexpr int NPTS = GS * GS;          // 16384 points per grid
constexpr float RES = 0.25f;
constexpr int NGRIDS = 16;
constexpr int BLOCK = 1024;
constexpr int ROWS_PER_BLOCK = BLOCK / GS;     // 8 query rows per block
constexpr int CHUNKS = NPTS / BLOCK;           // 16 chunks per (grid,dir)
constexpr int NBLOCKS = NGRIDS * 2 * CHUNKS;   // 512
constexpr int SLAB_ROWS = 12;                  // 8 query rows + 2 halo each side
constexpr float DONE_THR = 0.5625f;            // (3*RES)^2: cells outside the
                                               // 5x5 superset window have
                                               // Chebyshev >= 3 -> planar >= this
}

// One thread per query point; 512 x 1024-thread blocks (2 blocks/CU = 32
// waves/CU). Block's <=12-row DB slab (6 KB) staged to LDS in one coalesced
// burst; phase A reads are imm-offset ds_read_b32.
// Phase A: 5x5 SUPERSET window at clamped base (rb,cb) — always in-grid,
// covers every in-grid cell at Chebyshev radius <= 2. Exact-done iff
// best <= (3*RES)^2 = 0.5625 (excluded cells have planar >= 0.5625).
// Straggler rate ~2e-5 on N(0,1) data -> phase B nearly never runs.
// Phase B: wave-cooperative straggler scan from GLOBAL memory; one pass with
// K = ceil(4*sqrt(bestA)) is exact (radius >= K -> planar >= bestA).
__global__ __launch_bounds__(BLOCK, 8) void chamfer_kernel(
    const float* __restrict__ pred, const float* __restrict__ gt,
    float* __restrict__ partial)
{
    __shared__ float slab[SLAB_ROWS * GS];     // 6144 B

    const int bid = blockIdx.x;
    const int chunk = bid & (CHUNKS - 1);
    const int pair = bid >> 4;             // CHUNKS = 16
    const int g = pair >> 1;
    const int dir = pair & 1;
    const float* __restrict__ A  = (dir == 0) ? gt + g * NPTS : pred + g * NPTS;
    const float* __restrict__ DB = (dir == 0) ? pred + g * NPTS : gt + g * NPTS;

    const int tid = threadIdx.x;
    const int r0 = chunk * ROWS_PER_BLOCK;
    const int rlo = max(r0 - 2, 0);
    const int rhi = min(r0 + ROWS_PER_BLOCK + 1, GS - 1);  // +2 halo
    const int nrow = rhi - rlo + 1;                        // <= 12

    // stage slab rows [rlo..rhi] as float4s: <=384 loads, fully coalesced
    if (tid < nrow * (GS / 4)) {
        const int row = tid >> 5;          // GS/4 = 32 quads per row
        const int c4  = tid & 31;
        reinterpret_cast<float4*>(slab)[tid] =
            reinterpret_cast<const float4*>(DB + (rlo + row) * GS)[c4];
    }
    __syncthreads();

    const int i = chunk * BLOCK + tid;
    const int ri = r0 + (tid >> 7);
    const int ci = tid & (GS - 1);
    const float za = A[i];

    // superset window base: clamp the BASE, not each cell
    const int rb = min(max(ri, 2), GS - 3);
    const int cb = min(max(ci, 2), GS - 3);
    const float* __restrict__ wbase = slab + (rb - 2 - rlo) * GS + (cb - 2);

    // per-axis planar terms (5 each)
    float dx2[5], dy2[5];
    #pragma unroll
    for (int t = 0; t < 5; ++t) {
        const float dx = (float)(ri - (rb - 2 + t)) * RES;
        dx2[t] = dx * dx;
        const float dy = (float)(ci - (cb - 2 + t)) * RES;
        dy2[t] = dy * dy;
    }

    // phase A: 25 ds_read_b32 with imm offsets off one base; per-row min fold
    float bacc[4] = {1e30f, 1e30f, 1e30f, 1e30f};
    #pragma unroll
    for (int a = 0; a < 5; ++a) {
        float rm0 = 1e30f, rm1 = 1e30f;
        #pragma unroll
        for (int b = 0; b < 5; ++b) {
            const float z = wbase[a * GS + b];      // ds imm offset a*512+b*4
            const float dz = za - z;
            const float v = fmaf(dz, dz, dy2[b]);
            if (b & 1) rm1 = fminf(rm1, v); else rm0 = fminf(rm0, v);
        }
        bacc[a & 3] = fminf(bacc[a & 3], fminf(rm0, rm1) + dx2[a]);
    }
    float best = fminf(fminf(bacc[0], bacc[1]), fminf(bacc[2], bacc[3]));

    // phase B: wave-cooperative straggler finish (rare), from global
    const int lane = tid & 63;
    const int lr = lane >> 3, lc = lane & 7;   // 8x8 lane tile
    unsigned long long pend = __ballot(best > DONE_THR);
    while (pend) {
        const int src = __ffsll(pend) - 1;
        pend &= pend - 1;
        const int qri = __shfl(ri, src);
        const int qci = __shfl(ci, src);
        const float qza = __shfl(za, src);
        const float qb  = __shfl(best, src);
        int K = (int)(4.0f * sqrtf(qb)) + 1;   // >= ceil(sqrt(qb)/RES)
        K = min(K, GS - 1);
        float m = 1e30f;
        for (int tr = -K; tr <= K; tr += 8) {
            const int dr = tr + lr;
            if (dr > K) continue;
            const int r = min(max(qri + dr, 0), GS - 1);
            const float dx = (float)(qri - r) * RES;
            const float dxx2 = dx * dx;
            const float* __restrict__ row = DB + r * GS;
            for (int tc = -K; tc <= K; tc += 8) {
                const int dc = tc + lc;
                if (dc > K) continue;
                const int c = min(max(qci + dc, 0), GS - 1);
                const float dy = (float)(qci - c) * RES;
                const float dz = qza - row[c];
                m = fminf(m, fmaf(dz, dz, fmaf(dy, dy, dxx2)));
            }
        }
        #pragma unroll
        for (int off = 32; off > 0; off >>= 1) m = fminf(m, __shfl_xor(m, off));
        if (lane == src) best = fminf(best, m);
    }

    // block sum-reduction -> one partial per block (no atomics)
    for (int off = 32; off > 0; off >>= 1) best += __shfl_down(best, off);
    __shared__ float wsum[BLOCK / 64];
    if ((tid & 63) == 0) wsum[tid >> 6] = best;
    __syncthreads();
    if (tid == 0) {
        float s = 0.0f;
        #pragma unroll
        for (int w = 0; w < BLOCK / 64; ++w) s += wsum[w];
        partial[bid] = s;
    }
}

__global__ __launch_bounds__(512) void reduce_kernel(
    const float* __restrict__ partial, float* __restrict__ out)
{
    const int tid = threadIdx.x;
    float s = partial[tid];                // NBLOCKS = 512
    for (int off = 32; off > 0; off >>= 1) s += __shfl_down(s, off);
    __shared__ float wsum[8];
    if ((tid & 63) == 0) wsum[tid >> 6] = s;
    __syncthreads();
    if (tid == 0) {
        float t = 0.0f;
        #pragma unroll
        for (int w = 0; w < 8; ++w) t += wsum[w];
        *out = t * (1.0f / NGRIDS);
    }
}

extern "C" void kernel_launch(void* const* d_in, const int* in_sizes, int n_in,
                              void* d_out, int out_size, void* d_ws, size_t ws_size,
                              hipStream_t stream) {
    const float* pred = (const float*)d_in[0];  // inputs (1,1,512,512)
    const float* gt   = (const float*)d_in[1];  // targets (1,512,512)
    float* partial = (float*)d_ws;              // 512 floats
    float* out = (float*)d_out;
    chamfer_kernel<<<NBLOCKS, BLOCK, 0, stream>>>(pred, gt, partial);
    reduce_kernel<<<1, 512, 0, stream>>>(partial, out);
}

// Round 12
// 17.449 us; speedup vs baseline: 1.2442x; 1.1604x over previous
//
#include <hip/hip_runtime.h>

namespace {
constexpr int GS = 128;
constexpr int NPTS = GS * GS;          // 16384 points per grid
constexpr float RES = 0.25f;
constexpr int NGRIDS = 16;
constexpr int BLOCK = 512;
constexpr int QROWS = 8;                       // query rows per block
constexpr int CHUNKS = GS / QROWS;             // 16 chunks per (grid,dir)
constexpr int NBLOCKS = NGRIDS * 2 * CHUNKS;   // 512
constexpr int SLAB_ROWS = QROWS + 6;           // 14 (8 query rows + 3 halo each side)
}

// VERTICAL QUERY PAIRING: each thread owns queries (ri,ci) and (ri+1,ci),
// which share 6 of 7 window rows -> one 8-row x 7-col window read serves both
// (56 ds_read vs 98: -43% LDS pipe, the dominant modeled cost in R9).
// 512 blocks x 512 threads (262144 threads x 2 queries; 16 waves/CU — phase-A
// latency is hidden by the 56-wide independent-load ILP burst, not TLP).
// Phase A: 8x7 SUPERSET window at clamped base rb8 (rows rb8-3..rb8+4, always
// in-grid, covers every in-grid cell at Chebyshev radius <= 3 of BOTH
// queries; the extra row is a real cell at true distance — harmless under
// min). Exact-done iff best <= (4*RES)^2 = 1.0. Phase B: wave-cooperative
// straggler scan from GLOBAL memory (rate ~2e-5/query at thr=1.0 — R11
// proved thr=0.5625 explodes this to ~5e-3: keep 1.0); one pass with
// K = ceil(4*sqrt(bestA)) is exact (radius >= K -> planar >= bestA).
__global__ __launch_bounds__(BLOCK, 8) void chamfer_kernel(
    const float* __restrict__ pred, const float* __restrict__ gt,
    float* __restrict__ partial)
{
    __shared__ float slab[SLAB_ROWS * GS];     // 7168 B

    const int bid = blockIdx.x;
    const int chunk = bid & (CHUNKS - 1);
    const int pair = bid >> 4;             // CHUNKS = 16
    const int g = pair >> 1;
    const int dir = pair & 1;
    const float* __restrict__ A  = (dir == 0) ? gt + g * NPTS : pred + g * NPTS;
    const float* __restrict__ DB = (dir == 0) ? pred + g * NPTS : gt + g * NPTS;

    const int tid = threadIdx.x;
    const int r0 = chunk * QROWS;
    const int rlo = max(r0 - 3, 0);
    const int rhi = min(r0 + QROWS + 2, GS - 1);   // r0..r0+7 queries, +3 halo
    const int nrow = rhi - rlo + 1;                // <= 14

    // stage slab rows [rlo..rhi] as float4s: <=448 loads, fully coalesced
    if (tid < nrow * (GS / 4)) {
        const int row = tid >> 5;          // GS/4 = 32 quads per row
        const int c4  = tid & 31;
        reinterpret_cast<float4*>(slab)[tid] =
            reinterpret_cast<const float4*>(DB + (rlo + row) * GS)[c4];
    }
    __syncthreads();

    const int ri = r0 + 2 * (tid >> 7);    // even row of the vertical pair
    const int ci = tid & (GS - 1);
    float za[2];
    za[0] = A[ri * GS + ci];
    za[1] = A[(ri + 1) * GS + ci];

    // pair window base: rows rb8-3..rb8+4 (always in-grid, covers both queries)
    const int rb8 = min(max(ri, 3), GS - 5);
    const int cb  = min(max(ci, 3), GS - 4);
    const float* __restrict__ wbase = slab + (rb8 - 3 - rlo) * GS + (cb - 3);

    // per-axis planar terms
    float dy2[7];
    #pragma unroll
    for (int t = 0; t < 7; ++t) {
        const float dy = (float)(ci - (cb - 3 + t)) * RES;
        dy2[t] = dy * dy;
    }
    float dx2q0[8], dx2q1[8];
    #pragma unroll
    for (int a = 0; a < 8; ++a) {
        const float dx0 = (float)(ri - (rb8 - 3 + a)) * RES;
        dx2q0[a] = dx0 * dx0;
        const float dx1 = dx0 + RES;       // (ri+1) - row
        dx2q1[a] = dx1 * dx1;
    }

    // phase A: 8 rows x 7 cols, read once, evaluated for both queries
    float acc0[2] = {1e30f, 1e30f};
    float acc1[2] = {1e30f, 1e30f};
    #pragma unroll
    for (int a = 0; a < 8; ++a) {
        float rm0a = 1e30f, rm0b = 1e30f, rm1a = 1e30f, rm1b = 1e30f;
        #pragma unroll
        for (int b = 0; b < 7; ++b) {
            const float z = wbase[a * GS + b];      // ds imm offset a*512+b*4
            const float d0 = za[0] - z;
            const float d1 = za[1] - z;
            const float v0 = fmaf(d0, d0, dy2[b]);
            const float v1 = fmaf(d1, d1, dy2[b]);
            if (b & 1) { rm0b = fminf(rm0b, v0); rm1b = fminf(rm1b, v1); }
            else       { rm0a = fminf(rm0a, v0); rm1a = fminf(rm1a, v1); }
        }
        acc0[a & 1] = fminf(acc0[a & 1], fminf(rm0a, rm0b) + dx2q0[a]);
        acc1[a & 1] = fminf(acc1[a & 1], fminf(rm1a, rm1b) + dx2q1[a]);
    }
    float best[2];
    best[0] = fminf(acc0[0], acc0[1]);
    best[1] = fminf(acc1[0], acc1[1]);

    // phase B: wave-cooperative straggler finish (rare), from global
    const int lane = tid & 63;
    const int lr = lane >> 3, lc = lane & 7;   // 8x8 lane tile
    #pragma unroll
    for (int j = 0; j < 2; ++j) {
        unsigned long long pend = __ballot(best[j] > 1.0f);
        while (pend) {
            const int src = __ffsll(pend) - 1;
            pend &= pend - 1;
            const int qri = __shfl(ri, src) + j;
            const int qci = __shfl(ci, src);
            const float qza = __shfl(za[j], src);
            const float qb  = __shfl(best[j], src);
            int K = (int)(4.0f * sqrtf(qb)) + 1;   // >= ceil(sqrt(qb)/RES)
            K = min(K, GS - 1);
            float m = 1e30f;
            for (int tr = -K; tr <= K; tr += 8) {
                const int dr = tr + lr;
                if (dr > K) continue;
                const int r = min(max(qri + dr, 0), GS - 1);
                const float dx = (float)(qri - r) * RES;
                const float dxx2 = dx * dx;
                const float* __restrict__ row = DB + r * GS;
                for (int tc = -K; tc <= K; tc += 8) {
                    const int dc = tc + lc;
                    if (dc > K) continue;
                    const int c = min(max(qci + dc, 0), GS - 1);
                    const float dy = (float)(qci - c) * RES;
                    const float dz = qza - row[c];
                    m = fminf(m, fmaf(dz, dz, fmaf(dy, dy, dxx2)));
                }
            }
            #pragma unroll
            for (int off = 32; off > 0; off >>= 1) m = fminf(m, __shfl_xor(m, off));
            if (lane == src) best[j] = fminf(best[j], m);
        }
    }

    // block sum-reduction -> one partial per block (no atomics)
    float s = best[0] + best[1];
    for (int off = 32; off > 0; off >>= 1) s += __shfl_down(s, off);
    __shared__ float wsum[BLOCK / 64];
    if ((tid & 63) == 0) wsum[tid >> 6] = s;
    __syncthreads();
    if (tid == 0) {
        float t = 0.0f;
        #pragma unroll
        for (int w = 0; w < BLOCK / 64; ++w) t += wsum[w];
        partial[bid] = t;
    }
}

__global__ __launch_bounds__(512) void reduce_kernel(
    const float* __restrict__ partial, float* __restrict__ out)
{
    const int tid = threadIdx.x;
    float s = partial[tid];                // NBLOCKS = 512
    for (int off = 32; off > 0; off >>= 1) s += __shfl_down(s, off);
    __shared__ float wsum[8];
    if ((tid & 63) == 0) wsum[tid >> 6] = s;
    __syncthreads();
    if (tid == 0) {
        float t = 0.0f;
        #pragma unroll
        for (int w = 0; w < 8; ++w) t += wsum[w];
        *out = t * (1.0f / NGRIDS);
    }
}

extern "C" void kernel_launch(void* const* d_in, const int* in_sizes, int n_in,
                              void* d_out, int out_size, void* d_ws, size_t ws_size,
                              hipStream_t stream) {
    const float* pred = (const float*)d_in[0];  // inputs (1,1,512,512)
    const float* gt   = (const float*)d_in[1];  // targets (1,512,512)
    float* partial = (float*)d_ws;              // 512 floats
    float* out = (float*)d_out;
    chamfer_kernel<<<NBLOCKS, BLOCK, 0, stream>>>(pred, gt, partial);
    reduce_kernel<<<1, 512, 0, stream>>>(partial, out);
}

// Round 13
// 15.750 us; speedup vs baseline: 1.3783x; 1.1079x over previous
//
#include <hip/hip_runtime.h>

namespace {
constexpr int GS = 128;
constexpr int NPTS = GS * GS;          // 16384 points per grid
constexpr float RES = 0.25f;
constexpr int NGRIDS = 16;
constexpr int BLOCK = 1024;
constexpr int ROWS_PER_BLOCK = BLOCK / GS;     // 8 query rows per block
constexpr int CHUNKS = NPTS / BLOCK;           // 16 chunks per (grid,dir)
constexpr int NBLOCKS = NGRIDS * 2 * CHUNKS;   // 512
constexpr int SLAB_ROWS = 14;                  // max rows a block's windows touch
}

// R9 structure (best known: 15.7 us) with ONE change: phase-A window reads
// are 4x ds_read_b64 per row (8-col even-aligned superset window) instead of
// 7x ds_read_b32 — 28 LDS instrs (512B each) vs 49 (256B each): -56% LDS-pipe
// cycles for +8% VALU. Everything else byte-identical to R9.
// Phase A: 7-row x 8-col SUPERSET window; rows rb-3..rb+3 (rb=clamp(ri,3,124)),
// cols cE..cE+7 with cE = min((clamp(ci,3,124)-3)&~1, 120) — always in-grid,
// covers every in-grid cell at Chebyshev radius <= 3 (extra cells are real
// cells at true distance: harmless under min). Exact-done iff best <=
// (4*RES)^2 = 1.0. Phase B: wave-cooperative straggler scan from GLOBAL
// memory (rate ~2e-5/query at thr=1.0); one pass with K = ceil(4*sqrt(bestA))
// is exact (radius >= K -> planar >= bestA).
__global__ __launch_bounds__(BLOCK, 8) void chamfer_kernel(
    const float* __restrict__ pred, const float* __restrict__ gt,
    float* __restrict__ partial)
{
    __shared__ float slab[SLAB_ROWS * GS];     // 7168 B

    const int bid = blockIdx.x;
    const int chunk = bid & (CHUNKS - 1);
    const int pair = bid >> 4;             // CHUNKS = 16
    const int g = pair >> 1;
    const int dir = pair & 1;
    const float* __restrict__ A  = (dir == 0) ? gt + g * NPTS : pred + g * NPTS;
    const float* __restrict__ DB = (dir == 0) ? pred + g * NPTS : gt + g * NPTS;

    const int tid = threadIdx.x;
    const int r0 = chunk * ROWS_PER_BLOCK;
    const int rlo = max(r0 - 3, 0);
    const int rhi = min(r0 + ROWS_PER_BLOCK + 2, GS - 1);  // r0+7 rows, +3 window
    const int nrow = rhi - rlo + 1;                        // <= 14

    // stage slab rows [rlo..rhi] as float4s: <=448 loads, fully coalesced
    if (tid < nrow * (GS / 4)) {
        const int row = tid >> 5;          // GS/4 = 32 quads per row
        const int c4  = tid & 31;
        reinterpret_cast<float4*>(slab)[tid] =
            reinterpret_cast<const float4*>(DB + (rlo + row) * GS)[c4];
    }
    __syncthreads();

    const int i = chunk * BLOCK + tid;
    const int ri = r0 + (tid >> 7);
    const int ci = tid & (GS - 1);
    const float za = A[i];

    // superset window: clamp the BASE, not each cell
    const int rb = min(max(ri, 3), GS - 4);
    const int cb = min(max(ci, 3), GS - 4);
    const int cE = min((cb - 3) & ~1, GS - 8);      // even, 8 cols all in-grid
    const float* __restrict__ wbase = slab + (rb - 3 - rlo) * GS + cE;

    // per-axis planar terms
    float dx2[7];
    #pragma unroll
    for (int t = 0; t < 7; ++t) {
        const float dx = (float)(ri - (rb - 3 + t)) * RES;
        dx2[t] = dx * dx;
    }
    float dy2[8];
    #pragma unroll
    for (int t = 0; t < 8; ++t) {
        const float dy = (float)(ci - (cE + t)) * RES;
        dy2[t] = dy * dy;
    }

    // phase A: 7 rows x 4 ds_read_b64 (8 cols); per-row min fold
    float bacc[4] = {1e30f, 1e30f, 1e30f, 1e30f};
    #pragma unroll
    for (int a = 0; a < 7; ++a) {
        const float2* rp = reinterpret_cast<const float2*>(wbase + a * GS);
        float rm0 = 1e30f, rm1 = 1e30f;
        #pragma unroll
        for (int t = 0; t < 4; ++t) {
            const float2 z2 = rp[t];                // ds_read_b64, imm offset
            const float d0 = za - z2.x;
            const float d1 = za - z2.y;
            rm0 = fminf(rm0, fmaf(d0, d0, dy2[2 * t]));
            rm1 = fminf(rm1, fmaf(d1, d1, dy2[2 * t + 1]));
        }
        bacc[a & 3] = fminf(bacc[a & 3], fminf(rm0, rm1) + dx2[a]);
    }
    float best = fminf(fminf(bacc[0], bacc[1]), fminf(bacc[2], bacc[3]));

    // phase B: wave-cooperative straggler finish (rare), from global
    const int lane = tid & 63;
    const int lr = lane >> 3, lc = lane & 7;   // 8x8 lane tile
    unsigned long long pend = __ballot(best > 1.0f);
    while (pend) {
        const int src = __ffsll(pend) - 1;
        pend &= pend - 1;
        const int qri = __shfl(ri, src);
        const int qci = __shfl(ci, src);
        const float qza = __shfl(za, src);
        const float qb  = __shfl(best, src);
        int K = (int)(4.0f * sqrtf(qb)) + 1;   // >= ceil(sqrt(qb)/RES)
        K = min(K, GS - 1);
        float m = 1e30f;
        for (int tr = -K; tr <= K; tr += 8) {
            const int dr = tr + lr;
            if (dr > K) continue;
            const int r = min(max(qri + dr, 0), GS - 1);
            const float dx = (float)(qri - r) * RES;
            const float dxx2 = dx * dx;
            const float* __restrict__ row = DB + r * GS;
            for (int tc = -K; tc <= K; tc += 8) {
                const int dc = tc + lc;
                if (dc > K) continue;
                const int c = min(max(qci + dc, 0), GS - 1);
                const float dy = (float)(qci - c) * RES;
                const float dz = qza - row[c];
                m = fminf(m, fmaf(dz, dz, fmaf(dy, dy, dxx2)));
            }
        }
        #pragma unroll
        for (int off = 32; off > 0; off >>= 1) m = fminf(m, __shfl_xor(m, off));
        if (lane == src) best = fminf(best, m);
    }

    // block sum-reduction -> one partial per block (no atomics)
    for (int off = 32; off > 0; off >>= 1) best += __shfl_down(best, off);
    __shared__ float wsum[BLOCK / 64];
    if ((tid & 63) == 0) wsum[tid >> 6] = best;
    __syncthreads();
    if (tid == 0) {
        float s = 0.0f;
        #pragma unroll
        for (int w = 0; w < BLOCK / 64; ++w) s += wsum[w];
        partial[bid] = s;
    }
}

__global__ __launch_bounds__(512) void reduce_kernel(
    const float* __restrict__ partial, float* __restrict__ out)
{
    const int tid = threadIdx.x;
    float s = partial[tid];                // NBLOCKS = 512
    for (int off = 32; off > 0; off >>= 1) s += __shfl_down(s, off);
    __shared__ float wsum[8];
    if ((tid & 63) == 0) wsum[tid >> 6] = s;
    __syncthreads();
    if (tid == 0) {
        float t = 0.0f;
        #pragma unroll
        for (int w = 0; w < 8; ++w) t += wsum[w];
        *out = t * (1.0f / NGRIDS);
    }
}

extern "C" void kernel_launch(void* const* d_in, const int* in_sizes, int n_in,
                              void* d_out, int out_size, void* d_ws, size_t ws_size,
                              hipStream_t stream) {
    const float* pred = (const float*)d_in[0];  // inputs (1,1,512,512)
    const float* gt   = (const float*)d_in[1];  // targets (1,512,512)
    float* partial = (float*)d_ws;              // 512 floats
    float* out = (float*)d_out;
    chamfer_kernel<<<NBLOCKS, BLOCK, 0, stream>>>(pred, gt, partial);
    reduce_kernel<<<1, 512, 0, stream>>>(partial, out);
}